// Round 10
// baseline (74.966 us; speedup 1.0000x reference)
//
#include <hip/hip_runtime.h>

// Fused upfirdn2d: up2(FIR12,H) -> up2(FIR12,W) -> +bias -> lrelu*sqrt2
//                  -> down2(FIR12,H) -> down2(FIR12,W)
// x: (32,128,64,64) f32.
// R10 = R9 (quarter-slice, NT=512, separate phases) with two counter-driven fixes:
//   (a) P2/P3 lane groups padded to 48 (multiple of 8): R9's /42 grouping made
//       8-lane b128 groups straddle (cg,il) boundaries -> conflicts 7.4e6->1.27e7.
//   (b) P4 back to 4-row tasks (18 reads / 16 outputs, R5-style) instead of
//       1-row tasks (12 reads / 4 outputs): P4 LDS wave-insts 48 -> 18.
//
// Index math:
//   z[i][c]  = sum_{j == i (mod 2)} (2*fu[j]) * x[(i-j)/2][c]
//   y[i][w]  = sum_{j == w (mod 2)} (2*fu[j]) * z[i][(w-j)/2]; lrelu(y+b)*g
//   yw[i][p] = sum_{j} fd[j] * y[i][2p+11-j]          (down-W; commutes w/ down-H)
//   out[o][p]= sum_{j} fd[j] * yw[2o+11-j][p]         (down-H)

#define NT 512
#define GAIN 1.41421356237309504880f
#define C1 (0.6f * GAIN)
#define C2 (0.4f * GAIN)

#define ZROWS 42              // quarter: out rows [o0,o0+16) -> z/y rows [2o0,2o0+42)
#define ZSTRIDE 84            // 336B = 80B mod 128 -> full rotation, row-walk
#define ZPAD 8                // local col p <-> real z col p-8 ; pads zeroed
#define YSTRIDE 148           // 592B = 80B mod 128 -> full rotation, row-walk
#define YWSTRIDE 68           // 272B = 16B mod 128 -> full rotation, row-walk

#define ZB_OFF 0
#define YB_OFF (ZROWS * ZSTRIDE)              // 3528
#define YW_OFF 0                              // yw[42][68]=2856 aliases zb (dead after P2)
#define LDS_FLOATS (YB_OFF + ZROWS * YSTRIDE) // 9744 floats = 38976 B -> 4 blk/CU

// wave-uniform float -> SGPR
__device__ __forceinline__ float sload(float v) {
    return __uint_as_float(__builtin_amdgcn_readfirstlane(__float_as_uint(v)));
}

__global__ __launch_bounds__(NT, 8) void fused_upfirdn_lrelu(
    const float* __restrict__ x,
    const float* __restrict__ bias,
    const float* __restrict__ upf,
    const float* __restrict__ dnf,
    float* __restrict__ out)
{
    extern __shared__ float lds[];
    float* zb = lds + ZB_OFF;
    float* yb = lds + YB_OFF;
    float* yw = lds + YW_OFF;

    const int t = threadIdx.x;
    const int bid = blockIdx.x;
    const int s = bid >> 2;           // slice = n*128 + c
    const int o0 = (bid & 3) << 4;    // 0,16,32,48
    const int c = s & 127;

    // filters + bias in SGPRs (uniform); fu pre-scaled by UP=2
    float fu[12], fd[12];
#pragma unroll
    for (int j = 0; j < 12; ++j) {
        fu[j] = sload(2.0f * upf[j]);
        fd[j] = sload(dnf[j]);
    }
    const float bv = sload(bias[c]);

    const float* xg = x + (size_t)s * 4096;
    float* outg = out + (size_t)s * 4096;

    // ---- P1: up-H from GLOBAL x -> z local rows [0,42).  t<336: task=(m,c4),
    //      z rows 2m,2m+1 from x rows M-5..M (M=o0+m), interior unchecked.
    //      t>=336: zero z pad cols [0,8) and [72,84). ----
    if (t < 336) {
        const int m = t >> 4;                 // 0..20
        const int c4 = (t & 15) << 2;
        const int M = o0 + m;
        float4 xv[6];
        if (M >= 5 && M <= 63) {              // interior: no bounds checks
#pragma unroll
            for (int d = 0; d < 6; ++d)
                xv[d] = *reinterpret_cast<const float4*>(xg + (M - 5 + d) * 64 + c4);
        } else {
#pragma unroll
            for (int d = 0; d < 6; ++d) {
                const int r = M - 5 + d;
                xv[d] = (r >= 0 && r <= 63)
                      ? *reinterpret_cast<const float4*>(xg + r * 64 + c4)
                      : make_float4(0.f, 0.f, 0.f, 0.f);
            }
        }
        float a0[4] = {0,0,0,0}, a1[4] = {0,0,0,0};
#pragma unroll
        for (int d = 0; d < 6; ++d) {         // tt = 5-d
            const float w0 = fu[2 * (5 - d)], w1 = fu[2 * (5 - d) + 1];
            a0[0] += w0 * xv[d].x; a0[1] += w0 * xv[d].y; a0[2] += w0 * xv[d].z; a0[3] += w0 * xv[d].w;
            a1[0] += w1 * xv[d].x; a1[1] += w1 * xv[d].y; a1[2] += w1 * xv[d].z; a1[3] += w1 * xv[d].w;
        }
        float* zr = zb + (2 * m) * ZSTRIDE + ZPAD + c4;
        *reinterpret_cast<float4*>(zr)           = make_float4(a0[0], a0[1], a0[2], a0[3]);
        *reinterpret_cast<float4*>(zr + ZSTRIDE) = make_float4(a1[0], a1[1], a1[2], a1[3]);
    } else {
        // 5 float4 pad-writes per row x 42 rows = 210 tasks over 176 threads
        for (int pt = t - 336; pt < 210; pt += 176) {
            const int rl = pt / 5;
            const int p = pt - rl * 5;
            const int col = (p < 2) ? (p << 2) : (72 + ((p - 2) << 2));
            *reinterpret_cast<float4*>(zb + rl * ZSTRIDE + col) = make_float4(0.f, 0.f, 0.f, 0.f);
        }
    }
    __syncthreads();

    // ---- P2: up-W + bias + lrelu -> y[42][148].  Groups of 48 (mult of 8!),
    //      il fast-varying: every 8-lane b128 group has uniform cg and
    //      row-walk stride 336B = 80B mod 128 -> conflict-free. t<432. ----
    if (t < 432) {
        const int cg = t / 48;                // 0..8
        const int il = t - cg * 48;
        if (il < ZROWS) {
            const int mbase = cg << 3;
            const float* zr = zb + il * ZSTRIDE + mbase;   // local col = real col + 8
            float zv[16];
#pragma unroll
            for (int q = 0; q < 4; ++q) {
                const float4 v = *reinterpret_cast<const float4*>(zr + (q << 2));
                zv[4 * q] = v.x; zv[4 * q + 1] = v.y; zv[4 * q + 2] = v.z; zv[4 * q + 3] = v.w;
            }
            float yv[16];
#pragma unroll
            for (int e = 0; e < 8; ++e) {     // m = mbase+e -> w = 2m, 2m+1
                float a0 = bv, a1 = bv;
#pragma unroll
                for (int tt = 0; tt < 6; ++tt) {
                    const float zz = zv[8 + e - tt];
                    a0 += fu[2 * tt]     * zz;
                    a1 += fu[2 * tt + 1] * zz;
                }
                yv[2 * e]     = C1 * a0 + C2 * fabsf(a0);   // g*lrelu
                yv[2 * e + 1] = C1 * a1 + C2 * fabsf(a1);
            }
            float* yr = yb + il * YSTRIDE + (mbase << 1);
#pragma unroll
            for (int q = 0; q < 4; ++q)
                *reinterpret_cast<float4*>(yr + (q << 2)) =
                    make_float4(yv[4 * q], yv[4 * q + 1], yv[4 * q + 2], yv[4 * q + 3]);
        }
    }
    __syncthreads();

    // ---- P3: down-W on y -> yw[42][64] (aliases zb).  Groups of 48,
    //      il fast-varying (592B stride mod 128 = 80B -> clean). t<384. ----
    if (t < 384) {
        const int cg = t / 48;                // 0..7 ; outputs p = 8cg..8cg+7
        const int il = t - cg * 48;
        if (il < ZROWS) {
            const float* yr = yb + il * YSTRIDE + (cg << 4);   // y cols 16cg..16cg+27
            float w[28];
#pragma unroll
            for (int q = 0; q < 7; ++q) {
                const float4 v = *reinterpret_cast<const float4*>(yr + (q << 2));
                w[4 * q] = v.x; w[4 * q + 1] = v.y; w[4 * q + 2] = v.z; w[4 * q + 3] = v.w;
            }
            float rv[8];
#pragma unroll
            for (int e = 0; e < 8; ++e) {     // p = 8cg+e : y cols 2p..2p+11
                float a = 0.0f;
#pragma unroll
                for (int j = 0; j < 12; ++j) a += fd[j] * w[2 * e + 11 - j];
                rv[e] = a;
            }
            float* wr = yw + il * YWSTRIDE + (cg << 3);
            *reinterpret_cast<float4*>(wr)     = make_float4(rv[0], rv[1], rv[2], rv[3]);
            *reinterpret_cast<float4*>(wr + 4) = make_float4(rv[4], rv[5], rv[6], rv[7]);
        }
    }
    __syncthreads();

    // ---- P4: down-H on yw -> GLOBAL out.  t<64: task=(eg, col4): 4 out rows
    //      x 4 cols from 18 yw rows (1.125 reads/output; R9's 1-row tasks
    //      cost 3.0).  col4 fast-varying: 128B-contiguous groups, clean. ----
    if (t < 64) {
        const int eg = t >> 4;                // 0..3 ; out rows o0+4eg..o0+4eg+3
        const int col4 = (t & 15) << 2;       // 0..60
        const float* wr = yw + (eg << 3) * YWSTRIDE + col4;    // yw rows 8eg..8eg+17
        float acc[4][4] = {{0,0,0,0},{0,0,0,0},{0,0,0,0},{0,0,0,0}};
#pragma unroll
        for (int r = 0; r < 18; ++r) {
            const float4 v = *reinterpret_cast<const float4*>(wr + r * YWSTRIDE);
#pragma unroll
            for (int e = 0; e < 4; ++e) {
                if (r >= 2 * e && r <= 2 * e + 11) {           // compile-time per (r,e)
                    const float ww = fd[11 - r + 2 * e];
                    acc[e][0] += ww * v.x; acc[e][1] += ww * v.y;
                    acc[e][2] += ww * v.z; acc[e][3] += ww * v.w;
                }
            }
        }
#pragma unroll
        for (int e = 0; e < 4; ++e)
            *reinterpret_cast<float4*>(outg + (o0 + (eg << 2) + e) * 64 + col4) =
                make_float4(acc[e][0], acc[e][1], acc[e][2], acc[e][3]);
    }
}

extern "C" void kernel_launch(void* const* d_in, const int* in_sizes, int n_in,
                              void* d_out, int out_size, void* d_ws, size_t ws_size,
                              hipStream_t stream) {
    const float* x    = (const float*)d_in[0];
    const float* bias = (const float*)d_in[1];
    const float* upf  = (const float*)d_in[2];
    const float* dnf  = (const float*)d_in[3];
    float* out = (float*)d_out;

    const int n_blocks = 32 * 128 * 4;   // four quarter-slices per (n,c)
    const size_t lds_bytes = (size_t)LDS_FLOATS * sizeof(float);
    hipLaunchKernelGGL(fused_upfirdn_lrelu, dim3(n_blocks), dim3(NT),
                       lds_bytes, stream, x, bias, upf, dnf, out);
}